// Round 1
// baseline (1276.287 us; speedup 1.0000x reference)
//
#include <hip/hip_runtime.h>
#include <math.h>

typedef __bf16 bf16x8 __attribute__((ext_vector_type(8)));
typedef float  f32x4  __attribute__((ext_vector_type(4)));

__device__ __forceinline__ ushort f2bf(float f) {
  union { float f; unsigned u; } v; v.f = f;
  unsigned r = v.u + 0x7FFFu + ((v.u >> 16) & 1u);
  return (ushort)(r >> 16);
}
__device__ __forceinline__ float bf2f(ushort s) {
  union { unsigned u; float f; } v; v.u = ((unsigned)s) << 16;
  return v.f;
}

// ---------------- weight transpose + bf16 convert: W[K][N] -> WT[N][K] ----------------
__global__ void wtrans_kernel(const float* __restrict__ W, ushort* __restrict__ WT,
                              int K, int N) {
  int idx = blockIdx.x * 256 + threadIdx.x;
  if (idx >= K * N) return;
  int n = idx / K, k = idx - n * K;
  WT[idx] = f2bf(W[(size_t)k * N + n]);
}

// ---------------- LayerNorm (one wave per row of 384) ----------------
// SHIFT: output rows in window order (LN1 + cyclic shift + window partition)
template<bool SHIFT, bool INBF16>
__global__ __launch_bounds__(256) void ln_kernel(const void* __restrict__ inp,
                                                 ushort* __restrict__ outp,
                                                 const float* __restrict__ gamma,
                                                 const float* __restrict__ beta) {
  const int lane = threadIdx.x & 63;
  const int row = blockIdx.x * 4 + (threadIdx.x >> 6);
  size_t src;
  if (SHIFT) {
    int b = row / 3136, rem = row - b * 3136;
    int win = rem / 49, n = rem - win * 49;
    int wh = win >> 3, ww = win & 7;
    int i = n / 7, j = n - (n / 7) * 7;
    int h = wh * 7 + i + 3; if (h >= 56) h -= 56;   // roll(-3): shifted hs reads (hs+3)%56
    int w = ww * 7 + j + 3; if (w >= 56) w -= 56;
    src = ((size_t)b * 3136 + h * 56 + w) * 384;
  } else {
    src = (size_t)row * 384;
  }
  float xv[6];
  float sum = 0.f, sq = 0.f;
#pragma unroll
  for (int t = 0; t < 6; t++) {
    int c = lane + t * 64;
    float f;
    if (INBF16) f = bf2f(((const ushort*)inp)[src + c]);
    else        f = ((const float*)inp)[src + c];
    xv[t] = f; sum += f; sq += f * f;
  }
#pragma unroll
  for (int o = 32; o; o >>= 1) { sum += __shfl_xor(sum, o); sq += __shfl_xor(sq, o); }
  float mean = sum * (1.f / 384.f);
  float var  = sq * (1.f / 384.f) - mean * mean;
  float inv  = rsqrtf(var + 1e-5f);
#pragma unroll
  for (int t = 0; t < 6; t++) {
    int c = lane + t * 64;
    outp[(size_t)row * 384 + c] = f2bf((xv[t] - mean) * inv * gamma[c] + beta[c]);
  }
}

// ---------------- bf16 MFMA GEMM: C[M][N] = A[M][K] * BT[N][K]^T + bias ----------------
#define EPI_QKV  0
#define EPI_PROJ 1
#define EPI_MLP1 2
#define EPI_MLP2 3

template<int EPI>
__global__ __launch_bounds__(256) void gemm_kernel(
    const ushort* __restrict__ A, const ushort* __restrict__ BT,
    const float* __restrict__ bias, void* __restrict__ Cout,
    const void* __restrict__ extra, int M, int N, int K) {
  __shared__ ushort As[128 * 32];
  __shared__ ushort Bs[128 * 32];
  const int tid = threadIdx.x;
  const int m0 = blockIdx.y * 128;
  const int n0 = blockIdx.x * 128;
  const int lane = tid & 63, wave = tid >> 6;
  const int wr = (wave >> 1) * 64, wc = (wave & 1) * 64;
  const int fr = lane & 15, fq = lane >> 4;
  f32x4 acc[4][4] = {};
  const int r0 = tid >> 2, p0 = (tid & 3) * 8;

  for (int kt = 0; kt < K; kt += 32) {
    __syncthreads();
    *(uint4*)&As[r0 * 32 + p0]        = *(const uint4*)&A [(size_t)(m0 + r0)      * K + kt + p0];
    *(uint4*)&Bs[r0 * 32 + p0]        = *(const uint4*)&BT[(size_t)(n0 + r0)      * K + kt + p0];
    *(uint4*)&As[(r0 + 64) * 32 + p0] = *(const uint4*)&A [(size_t)(m0 + r0 + 64) * K + kt + p0];
    *(uint4*)&Bs[(r0 + 64) * 32 + p0] = *(const uint4*)&BT[(size_t)(n0 + r0 + 64) * K + kt + p0];
    __syncthreads();
    bf16x8 a[4], b[4];
#pragma unroll
    for (int i = 0; i < 4; i++) a[i] = *(const bf16x8*)&As[(wr + i * 16 + fr) * 32 + fq * 8];
#pragma unroll
    for (int i = 0; i < 4; i++) b[i] = *(const bf16x8*)&Bs[(wc + i * 16 + fr) * 32 + fq * 8];
#pragma unroll
    for (int i = 0; i < 4; i++)
#pragma unroll
      for (int j = 0; j < 4; j++)
        acc[i][j] = __builtin_amdgcn_mfma_f32_16x16x32_bf16(a[i], b[j], acc[i][j], 0, 0, 0);
  }

#pragma unroll
  for (int i = 0; i < 4; i++) {
#pragma unroll
    for (int j = 0; j < 4; j++) {
      f32x4 v = acc[i][j];
      const int row0 = m0 + wr + i * 16 + fq * 4;
      const int col  = n0 + wc + j * 16 + fr;
      const float bcol = bias[col];
#pragma unroll
      for (int r = 0; r < 4; r++) {
        const int m = row0 + r;
        float val = v[r] + bcol;
        if constexpr (EPI == EPI_QKV) {
          ((ushort*)Cout)[(size_t)m * N + col] = f2bf(val);
        } else if constexpr (EPI == EPI_PROJ) {
          // window reverse + un-shift scatter + residual (fp32 trunk)
          int b_ = m / 3136, rem = m - b_ * 3136;
          int win = rem / 49, n = rem - win * 49;
          int wh = win >> 3, ww = win & 7;
          int ii = n / 7, jj = n - (n / 7) * 7;
          int h = wh * 7 + ii + 3; if (h >= 56) h -= 56;
          int w = ww * 7 + jj + 3; if (w >= 56) w -= 56;
          size_t dst = ((size_t)b_ * 3136 + h * 56 + w) * 384 + col;
          ((float*)Cout)[dst] = ((const float*)extra)[dst] + val;
        } else if constexpr (EPI == EPI_MLP1) {
          float g = 0.5f * val * (1.f + erff(val * 0.70710678118654752f));
          ((ushort*)Cout)[(size_t)m * N + col] = f2bf(g);
        } else { // MLP2: + residual x1 (fp32), write fp32 out
          ((float*)Cout)[(size_t)m * N + col] =
              val + ((const float*)extra)[(size_t)m * N + col];
        }
      }
    }
  }
}

// ---------------- windowed attention: one wave per (window, head) ----------------
__global__ __launch_bounds__(64) void attn_kernel(
    const ushort* __restrict__ qkv, const float* __restrict__ bias_table,
    ushort* __restrict__ outp) {
  __shared__ float ks[49 * 32];
  __shared__ float vs[49 * 32];
  __shared__ float S[49 * 49];
  __shared__ float btab[169];
  __shared__ int   rgn[49];
  const int bw = blockIdx.x, head = blockIdx.y;
  const int lane = threadIdx.x;
  const ushort* base = qkv + (size_t)bw * 49 * 1152 + head * 32;

  for (int t = lane; t < 49 * 32; t += 64) {
    int r = t >> 5, d = t & 31;
    ks[t] = bf2f(base[(size_t)r * 1152 + 384 + d]);
    vs[t] = bf2f(base[(size_t)r * 1152 + 768 + d]);
  }
  for (int t = lane; t < 169; t += 64) btab[t] = bias_table[t * 12 + head];
  {
    int win = bw & 63, wh = win >> 3, ww = win & 7;
    if (lane < 49) {
      int i = lane / 7, j = lane - (lane / 7) * 7;
      int hs = wh * 7 + i, wsft = ww * 7 + j;
      int bh = (hs < 49) ? 0 : (hs < 53 ? 1 : 2);
      int bv = (wsft < 49) ? 0 : (wsft < 53 ? 1 : 2);
      rgn[lane] = bh * 3 + bv;
    }
  }
  __syncthreads();

  if (lane < 49) {
    float4 q4[8];
    const ushort* qp = base + (size_t)lane * 1152;
#pragma unroll
    for (int t = 0; t < 8; t++) {
      ushort4 u = *(const ushort4*)(qp + t * 4);
      q4[t] = make_float4(bf2f(u.x), bf2f(u.y), bf2f(u.z), bf2f(u.w));
    }
    const int i_n = lane / 7, j_n = lane - (lane / 7) * 7;
    const int rn = rgn[lane];
    float mx = -1e30f;
    for (int m_ = 0; m_ < 49; m_++) {
      const float4* kk = (const float4*)&ks[m_ * 32];
      float dot = 0.f;
#pragma unroll
      for (int t = 0; t < 8; t++) {
        float4 kv = kk[t];
        dot += q4[t].x * kv.x + q4[t].y * kv.y + q4[t].z * kv.z + q4[t].w * kv.w;
      }
      int im = m_ / 7, jm = m_ - (m_ / 7) * 7;
      float s = dot * 0.17677669529663689f
              + btab[(i_n - im + 6) * 13 + (j_n - jm + 6)]
              + ((rn == rgn[m_]) ? 0.f : -100.f);
      S[lane * 49 + m_] = s;
      mx = fmaxf(mx, s);
    }
    float sum = 0.f;
    for (int m_ = 0; m_ < 49; m_++) {
      float e = __expf(S[lane * 49 + m_] - mx);
      S[lane * 49 + m_] = e;
      sum += e;
    }
    float4 o4[8] = {};
    for (int m_ = 0; m_ < 49; m_++) {
      float p = S[lane * 49 + m_];
      const float4* vv = (const float4*)&vs[m_ * 32];
#pragma unroll
      for (int t = 0; t < 8; t++) {
        float4 w = vv[t];
        o4[t].x += p * w.x; o4[t].y += p * w.y; o4[t].z += p * w.z; o4[t].w += p * w.w;
      }
    }
    float inv = 1.f / sum;
    ushort* op = outp + (size_t)(bw * 49 + lane) * 384 + head * 32;
#pragma unroll
    for (int t = 0; t < 8; t++) {
      ushort4 u;
      u.x = f2bf(o4[t].x * inv); u.y = f2bf(o4[t].y * inv);
      u.z = f2bf(o4[t].z * inv); u.w = f2bf(o4[t].w * inv);
      *(ushort4*)(op + t * 4) = u;
    }
  }
}

extern "C" void kernel_launch(void* const* d_in, const int* in_sizes, int n_in,
                              void* d_out, int out_size, void* d_ws, size_t ws_size,
                              hipStream_t stream) {
  (void)in_sizes; (void)n_in; (void)out_size; (void)ws_size;
  const float* x      = (const float*)d_in[0];
  const float* W_qkv  = (const float*)d_in[1];
  const float* b_qkv  = (const float*)d_in[2];
  const float* W_proj = (const float*)d_in[3];
  const float* b_proj = (const float*)d_in[4];
  const float* btab   = (const float*)d_in[5];
  const float* gamma1 = (const float*)d_in[6];
  const float* beta1  = (const float*)d_in[7];
  const float* gamma2 = (const float*)d_in[8];
  const float* beta2  = (const float*)d_in[9];
  const float* W_mlp1 = (const float*)d_in[10];
  const float* b_mlp1 = (const float*)d_in[11];
  const float* W_mlp2 = (const float*)d_in[12];
  const float* b_mlp2 = (const float*)d_in[13];

  const int M = 100352;  // 32 * 3136 token rows

  char* ws = (char*)d_ws;
  ushort* WqkvT  = (ushort*)ws; ws += (size_t)1152 * 384 * 2;
  ushort* WprojT = (ushort*)ws; ws += (size_t)384 * 384 * 2;
  ushort* Wm1T   = (ushort*)ws; ws += (size_t)1536 * 384 * 2;
  ushort* Wm2T   = (ushort*)ws; ws += (size_t)384 * 1536 * 2;
  float*  x1     = (float*)ws;  ws += (size_t)M * 384 * 4;   // fp32 residual trunk
  ushort* h2     = (ushort*)ws; ws += (size_t)M * 384 * 2;
  ushort* bufB   = (ushort*)ws;                               // 308,281,344-byte overlay region
  ushort* xw     = bufB;                                      // [M][384]   (phase 1-2)
  ushort* qkv    = bufB + (size_t)M * 384;                    // [M][1152]  (phase 2-3)
  ushort* attn_o = bufB;                                      // [M][384]   (phase 3-4, over xw)
  ushort* g      = bufB;                                      // [M][1536]  (phase 6-7, over all)

  wtrans_kernel<<<(384 * 1152 + 255) / 256, 256, 0, stream>>>(W_qkv,  WqkvT,  384, 1152);
  wtrans_kernel<<<(384 * 384  + 255) / 256, 256, 0, stream>>>(W_proj, WprojT, 384, 384);
  wtrans_kernel<<<(384 * 1536 + 255) / 256, 256, 0, stream>>>(W_mlp1, Wm1T,   384, 1536);
  wtrans_kernel<<<(1536 * 384 + 255) / 256, 256, 0, stream>>>(W_mlp2, Wm2T,   1536, 384);

  ln_kernel<true,  false><<<M / 4, 256, 0, stream>>>(x, xw, gamma1, beta1);
  gemm_kernel<EPI_QKV ><<<dim3(1152 / 128, M / 128), 256, 0, stream>>>(xw, WqkvT, b_qkv, qkv, nullptr, M, 1152, 384);
  attn_kernel<<<dim3(2048, 12), 64, 0, stream>>>(qkv, btab, attn_o);
  gemm_kernel<EPI_PROJ><<<dim3(384 / 128, M / 128), 256, 0, stream>>>(attn_o, WprojT, b_proj, x1, x, M, 384, 384);
  ln_kernel<false, false><<<M / 4, 256, 0, stream>>>(x1, h2, gamma2, beta2);
  gemm_kernel<EPI_MLP1><<<dim3(1536 / 128, M / 128), 256, 0, stream>>>(h2, Wm1T, b_mlp1, g, nullptr, M, 1536, 384);
  gemm_kernel<EPI_MLP2><<<dim3(384 / 128, M / 128), 256, 0, stream>>>(g, Wm2T, b_mlp2, d_out, x1, M, 384, 1536);
}

// Round 3
// 1075.326 us; speedup vs baseline: 1.1869x; 1.1869x over previous
//
#include <hip/hip_runtime.h>
#include <math.h>

typedef __bf16 bf16x8 __attribute__((ext_vector_type(8)));
typedef float  f32x4  __attribute__((ext_vector_type(4)));

__device__ __forceinline__ ushort f2bf(float f) {
  union { float f; unsigned u; } v; v.f = f;
  unsigned r = v.u + 0x7FFFu + ((v.u >> 16) & 1u);
  return (ushort)(r >> 16);
}
__device__ __forceinline__ float bf2f(ushort s) {
  union { unsigned u; float f; } v; v.u = ((unsigned)s) << 16;
  return v.f;
}

__device__ __forceinline__ void gload_lds16(const ushort* g, ushort* l) {
  __builtin_amdgcn_global_load_lds((const __attribute__((address_space(1))) void*)g,
                                   (__attribute__((address_space(3))) void*)l, 16, 0, 0);
}

// ---------------- weight transpose + bf16 convert: W[K][N] -> WT[N][K] ----------------
__global__ void wtrans_kernel(const float* __restrict__ W, ushort* __restrict__ WT,
                              int K, int N) {
  int idx = blockIdx.x * 256 + threadIdx.x;
  if (idx >= K * N) return;
  int n = idx / K, k = idx - n * K;
  WT[idx] = f2bf(W[(size_t)k * N + n]);
}

// ---------------- LayerNorm (one wave per row of 384) ----------------
template<bool SHIFT, bool INBF16>
__global__ __launch_bounds__(256) void ln_kernel(const void* __restrict__ inp,
                                                 ushort* __restrict__ outp,
                                                 const float* __restrict__ gamma,
                                                 const float* __restrict__ beta) {
  const int lane = threadIdx.x & 63;
  const int row = blockIdx.x * 4 + (threadIdx.x >> 6);
  size_t src;
  if (SHIFT) {
    int b = row / 3136, rem = row - b * 3136;
    int win = rem / 49, n = rem - win * 49;
    int wh = win >> 3, ww = win & 7;
    int i = n / 7, j = n - (n / 7) * 7;
    int h = wh * 7 + i + 3; if (h >= 56) h -= 56;
    int w = ww * 7 + j + 3; if (w >= 56) w -= 56;
    src = ((size_t)b * 3136 + h * 56 + w) * 384;
  } else {
    src = (size_t)row * 384;
  }
  float xv[6];
  float sum = 0.f, sq = 0.f;
#pragma unroll
  for (int t = 0; t < 6; t++) {
    int c = lane + t * 64;
    float f;
    if (INBF16) f = bf2f(((const ushort*)inp)[src + c]);
    else        f = ((const float*)inp)[src + c];
    xv[t] = f; sum += f; sq += f * f;
  }
#pragma unroll
  for (int o = 32; o; o >>= 1) { sum += __shfl_xor(sum, o); sq += __shfl_xor(sq, o); }
  float mean = sum * (1.f / 384.f);
  float var  = sq * (1.f / 384.f) - mean * mean;
  float inv  = rsqrtf(var + 1e-5f);
#pragma unroll
  for (int t = 0; t < 6; t++) {
    int c = lane + t * 64;
    outp[(size_t)row * 384 + c] = f2bf((xv[t] - mean) * inv * gamma[c] + beta[c]);
  }
}

// ---------------- bf16 MFMA GEMM: C[M][N] = A[M][K] * BT[N][K]^T + bias ----------------
// Double-buffered LDS, global_load_lds staging, ONE explicit vmcnt(0)+barrier per K-tile.
#define EPI_QKV  0
#define EPI_PROJ 1
#define EPI_MLP1 2
#define EPI_MLP2 3

template<int EPI>
__global__ __launch_bounds__(256) void gemm_kernel(
    const ushort* __restrict__ A, const ushort* __restrict__ BT,
    const float* __restrict__ bias, void* __restrict__ Cout,
    const void* __restrict__ extra, int M, int N, int K, int nbn, int cpx) {
  __shared__ ushort As[2][128 * 32];
  __shared__ ushort Bs[2][128 * 32];
  const int tid = threadIdx.x;
  // bijective XCD swizzle (nwg % 8 == 0, verified host-side)
  const int flat = blockIdx.x;
  const int wg = (flat & 7) * cpx + (flat >> 3);
  const int bm = wg / nbn, bn = wg - bm * nbn;
  const int m0 = bm * 128, n0 = bn * 128;
  const int lane = tid & 63, wave = tid >> 6;
  const int wr = (wave >> 1) * 64, wc = (wave & 1) * 64;
  const int fr = lane & 15, fq = lane >> 4;
  f32x4 acc[4][4] = {};

  // staging: wave stages rows [wave*32, wave*32+32) of As and Bs (linear lane order)
  const size_t a_off = (size_t)(m0 + wave * 32 + (lane >> 2)) * K + (lane & 3) * 8;
  const size_t b_off = (size_t)(n0 + wave * 32 + (lane >> 2)) * K + (lane & 3) * 8;

#define STAGE(c, kt_) do {                                        \
    const ushort* ga = A  + a_off + (kt_);                        \
    const ushort* gb = BT + b_off + (kt_);                        \
    gload_lds16(ga,          &As[c][wave * 1024]);                \
    gload_lds16(ga + 16 * K, &As[c][wave * 1024 + 512]);          \
    gload_lds16(gb,          &Bs[c][wave * 1024]);                \
    gload_lds16(gb + 16 * K, &Bs[c][wave * 1024 + 512]);          \
  } while (0)

  STAGE(0, 0);
  asm volatile("s_waitcnt vmcnt(0)" ::: "memory");
  __syncthreads();

  int cur = 0;
  for (int kt = 0; kt < K; kt += 32) {
    if (kt + 32 < K) STAGE(cur ^ 1, kt + 32);
    bf16x8 a[4], b[4];
#pragma unroll
    for (int i = 0; i < 4; i++) a[i] = *(const bf16x8*)&As[cur][(wr + i * 16 + fr) * 32 + fq * 8];
#pragma unroll
    for (int i = 0; i < 4; i++) b[i] = *(const bf16x8*)&Bs[cur][(wc + i * 16 + fr) * 32 + fq * 8];
#pragma unroll
    for (int i = 0; i < 4; i++)
#pragma unroll
      for (int j = 0; j < 4; j++)
        acc[i][j] = __builtin_amdgcn_mfma_f32_16x16x32_bf16(a[i], b[j], acc[i][j], 0, 0, 0);
    // staged tile (kt+32) complete + all waves done reading buf[cur]
    asm volatile("s_waitcnt vmcnt(0)" ::: "memory");
    __syncthreads();
    cur ^= 1;
  }
#undef STAGE

#pragma unroll
  for (int i = 0; i < 4; i++) {
#pragma unroll
    for (int r = 0; r < 4; r++) {
      const int m = m0 + wr + i * 16 + fq * 4 + r;
      size_t rowbase;
      if constexpr (EPI == EPI_PROJ) {
        int b_ = m / 3136, rem = m - b_ * 3136;
        int win = rem / 49, nn = rem - win * 49;
        int wh = win >> 3, ww = win & 7;
        int ii = nn / 7, jj = nn - (nn / 7) * 7;
        int h = wh * 7 + ii + 3; if (h >= 56) h -= 56;
        int w = ww * 7 + jj + 3; if (w >= 56) w -= 56;
        rowbase = ((size_t)b_ * 3136 + h * 56 + w) * 384;
      } else {
        rowbase = (size_t)m * N;
      }
#pragma unroll
      for (int j = 0; j < 4; j++) {
        const int col = n0 + wc + j * 16 + fr;
        float val = acc[i][j][r] + bias[col];
        if constexpr (EPI == EPI_QKV) {
          ((ushort*)Cout)[rowbase + col] = f2bf(val);
        } else if constexpr (EPI == EPI_PROJ) {
          ((float*)Cout)[rowbase + col] = ((const float*)extra)[rowbase + col] + val;
        } else if constexpr (EPI == EPI_MLP1) {
          float g = 0.5f * val * (1.f + erff(val * 0.70710678118654752f));
          ((ushort*)Cout)[rowbase + col] = f2bf(g);
        } else { // MLP2
          ((float*)Cout)[rowbase + col] = val + ((const float*)extra)[rowbase + col];
        }
      }
    }
  }
}

// ---------------- windowed attention: streaming softmax, 2 waves/block ----------------
__global__ __launch_bounds__(128) void attn_kernel(
    const ushort* __restrict__ qkv, const float* __restrict__ bias_table,
    ushort* __restrict__ outp) {
  __shared__ float ksv[2][49 * 64];   // per wave: row m -> [K 0..31 | V 32..63]
  __shared__ float btab[2][169];
  __shared__ char  rgn[2][52];
  const int wave = threadIdx.x >> 6, lane = threadIdx.x & 63;
  const int gw = blockIdx.x * 2 + wave;        // 0..24575
  const int bw = gw / 12, head = gw - bw * 12;
  const ushort* base = qkv + (size_t)bw * 49 * 1152 + head * 32;

  for (int t = lane; t < 784; t += 64) {
    int row = t >> 4;
    int c0  = (t & 15) * 4;
    int src_c = (c0 < 32) ? (384 + c0) : (736 + c0);
    ushort4 u = *(const ushort4*)(base + (size_t)row * 1152 + src_c);
    float4 f = make_float4(bf2f(u.x), bf2f(u.y), bf2f(u.z), bf2f(u.w));
    *(float4*)&ksv[wave][row * 64 + c0] = f;
  }
  for (int t = lane; t < 169; t += 64) btab[wave][t] = bias_table[t * 12 + head];
  {
    int win = bw & 63, wh = win >> 3, ww = win & 7;
    if (lane < 49) {
      int i = lane / 7, j = lane - (lane / 7) * 7;
      int hs = wh * 7 + i, wsf = ww * 7 + j;
      int bh = (hs < 49) ? 0 : (hs < 53 ? 1 : 2);
      int bv = (wsf < 49) ? 0 : (wsf < 53 ? 1 : 2);
      rgn[wave][lane] = (char)(bh * 3 + bv);
    }
  }
  __syncthreads();

  const int n = (lane < 49) ? lane : 48;
  float4 q4[8];
  {
    const ushort* qp = base + (size_t)n * 1152;
#pragma unroll
    for (int t = 0; t < 8; t++) {
      ushort4 u = *(const ushort4*)(qp + t * 4);
      q4[t] = make_float4(bf2f(u.x) * 0.17677669529663689f, bf2f(u.y) * 0.17677669529663689f,
                          bf2f(u.z) * 0.17677669529663689f, bf2f(u.w) * 0.17677669529663689f);
    }
  }
  const int rn = rgn[wave][n];
  const int i_n = n / 7, j_n = n - (n / 7) * 7;
  const float* bt = &btab[wave][(i_n + 6) * 13 + (j_n + 6)];
  const float* kb = &ksv[wave][0];

  float4 o4[8] = {};
  float sum = 0.f;
  for (int im = 0; im < 7; im++) {
#pragma unroll
    for (int jm = 0; jm < 7; jm++) {
      const int m_ = im * 7 + jm;
      const float4* kk = (const float4*)(kb + m_ * 64);
      float4 d = {};
#pragma unroll
      for (int t = 0; t < 8; t++) {
        float4 kv = kk[t];
        d.x += q4[t].x * kv.x; d.y += q4[t].y * kv.y;
        d.z += q4[t].z * kv.z; d.w += q4[t].w * kv.w;
      }
      float s = (d.x + d.y) + (d.z + d.w) + bt[-im * 13 - jm]
              + ((rn == rgn[wave][m_]) ? 0.f : -100.f);
      float e = __expf(s);
      sum += e;
      const float4* vv = (const float4*)(kb + m_ * 64 + 32);
#pragma unroll
      for (int t = 0; t < 8; t++) {
        float4 w = vv[t];
        o4[t].x += e * w.x; o4[t].y += e * w.y;
        o4[t].z += e * w.z; o4[t].w += e * w.w;
      }
    }
  }
  if (lane < 49) {
    float inv = 1.f / sum;
    ushort* op = outp + (size_t)(bw * 49 + n) * 384 + head * 32;
#pragma unroll
    for (int t = 0; t < 8; t++) {
      ushort4 u;
      u.x = f2bf(o4[t].x * inv); u.y = f2bf(o4[t].y * inv);
      u.z = f2bf(o4[t].z * inv); u.w = f2bf(o4[t].w * inv);
      *(ushort4*)(op + t * 4) = u;
    }
  }
}

extern "C" void kernel_launch(void* const* d_in, const int* in_sizes, int n_in,
                              void* d_out, int out_size, void* d_ws, size_t ws_size,
                              hipStream_t stream) {
  (void)in_sizes; (void)n_in; (void)out_size; (void)ws_size;
  const float* x      = (const float*)d_in[0];
  const float* W_qkv  = (const float*)d_in[1];
  const float* b_qkv  = (const float*)d_in[2];
  const float* W_proj = (const float*)d_in[3];
  const float* b_proj = (const float*)d_in[4];
  const float* btab   = (const float*)d_in[5];
  const float* gamma1 = (const float*)d_in[6];
  const float* beta1  = (const float*)d_in[7];
  const float* gamma2 = (const float*)d_in[8];
  const float* beta2  = (const float*)d_in[9];
  const float* W_mlp1 = (const float*)d_in[10];
  const float* b_mlp1 = (const float*)d_in[11];
  const float* W_mlp2 = (const float*)d_in[12];
  const float* b_mlp2 = (const float*)d_in[13];

  const int M = 100352;  // 32 * 3136 token rows

  char* ws = (char*)d_ws;
  ushort* WqkvT  = (ushort*)ws; ws += (size_t)1152 * 384 * 2;
  ushort* WprojT = (ushort*)ws; ws += (size_t)384 * 384 * 2;
  ushort* Wm1T   = (ushort*)ws; ws += (size_t)1536 * 384 * 2;
  ushort* Wm2T   = (ushort*)ws; ws += (size_t)384 * 1536 * 2;
  float*  x1     = (float*)ws;  ws += (size_t)M * 384 * 4;   // fp32 residual trunk
  ushort* h2     = (ushort*)ws; ws += (size_t)M * 384 * 2;
  ushort* bufB   = (ushort*)ws;                               // overlay region
  ushort* xw     = bufB;                                      // [M][384]
  ushort* qkv    = bufB + (size_t)M * 384;                    // [M][1152]
  ushort* attn_o = bufB;                                      // [M][384]  (over xw)
  ushort* g      = bufB;                                      // [M][1536] (over all)

  wtrans_kernel<<<(384 * 1152 + 255) / 256, 256, 0, stream>>>(W_qkv,  WqkvT,  384, 1152);
  wtrans_kernel<<<(384 * 384  + 255) / 256, 256, 0, stream>>>(W_proj, WprojT, 384, 384);
  wtrans_kernel<<<(384 * 1536 + 255) / 256, 256, 0, stream>>>(W_mlp1, Wm1T,   384, 1536);
  wtrans_kernel<<<(1536 * 384 + 255) / 256, 256, 0, stream>>>(W_mlp2, Wm2T,   1536, 384);

  ln_kernel<true,  false><<<M / 4, 256, 0, stream>>>(x, xw, gamma1, beta1);

  {
    int nbn = 1152 / 128, nwg = (M / 128) * nbn;
    gemm_kernel<EPI_QKV ><<<nwg, 256, 0, stream>>>(xw, WqkvT, b_qkv, qkv, nullptr, M, 1152, 384, nbn, nwg / 8);
  }
  attn_kernel<<<12288, 128, 0, stream>>>(qkv, btab, attn_o);
  {
    int nbn = 384 / 128, nwg = (M / 128) * nbn;
    gemm_kernel<EPI_PROJ><<<nwg, 256, 0, stream>>>(attn_o, WprojT, b_proj, x1, x, M, 384, 384, nbn, nwg / 8);
  }
  ln_kernel<false, false><<<M / 4, 256, 0, stream>>>(x1, h2, gamma2, beta2);
  {
    int nbn = 1536 / 128, nwg = (M / 128) * nbn;
    gemm_kernel<EPI_MLP1><<<nwg, 256, 0, stream>>>(h2, Wm1T, b_mlp1, g, nullptr, M, 1536, 384, nbn, nwg / 8);
  }
  {
    int nbn = 384 / 128, nwg = (M / 128) * nbn;
    gemm_kernel<EPI_MLP2><<<nwg, 256, 0, stream>>>(g, Wm2T, b_mlp2, d_out, x1, M, 384, 1536, nbn, nwg / 8);
  }
}